// Round 14
// baseline (34.788 us; speedup 1.0000x reference)
//
#include <hip/hip_runtime.h>
#include <math.h>

#define TEMP_INV (1.0f / 0.07f)   // also the fixed LSE shift M (sims bounded by 1/T)

typedef float vf4 __attribute__((ext_vector_type(4)));

#define DOT4(a, n) ((a).x*(n).x + (a).y*(n).y + (a).z*(n).z + (a).w*(n).w)

__device__ __forceinline__ float wave_reduce_sum(float v) {
    #pragma unroll
    for (int off = 32; off; off >>= 1) v += __shfl_down(v, off);
    return v;
}

__device__ __forceinline__ float wave_reduce_max(float v) {
    #pragma unroll
    for (int off = 32; off; off >>= 1) v = fmaxf(v, __shfl_down(v, off));
    return v;
}

// fold two value-streams into one register: lanes with (lane&span) carry hi.
__device__ __forceinline__ float merge2(float lo, float hi, int span, int lane) {
    float a = lo + __shfl_xor(lo, span);
    float b = hi + __shfl_xor(hi, span);
    return (lane & span) ? b : a;
}

// Wave-cooperative 64-ary lower_bound: first pos in [0,N] with idx[pos]>=target.
// ~3-4 rounds of {1 coalesced load + ballot} for N=131072 (64^3 > N).
__device__ __forceinline__ int wave_lb(const int* __restrict__ idx, int N,
                                       int target, int lane) {
    int lo = 0, hi = N;               // lb in [lo, hi]
    while (hi > lo) {
        int R = hi - lo;
        int step = (R + 62) / 63;     // 64 samples cover [lo, lo+63*step] >= hi
        int pos = lo + lane * step;
        int v = (pos < N) ? idx[pos] : 0x7fffffff;
        unsigned long long m = __ballot(v < target);
        int p = __popcll(m);          // prefix of lanes strictly left of boundary
        int nlo = (p > 0) ? (lo + (p - 1) * step + 1) : lo;
        int nhi = (p < 64) ? min(hi, min(lo + p * step, N)) : hi;
        lo = nlo; hi = nhi;
    }
    return lo;
}

// One wave per batch row b: anchor row pinned in registers, stream the
// contiguous negative segment, inline fixed-M LSE. No raw[]/seg_start/idx
// traffic in the hot loop.
__global__ void k_fused(const float* __restrict__ A, const float* __restrict__ P,
                        const float* __restrict__ Ng, const int* __restrict__ idx,
                        float* __restrict__ loss_i, float* __restrict__ corr,
                        int B, int N) {
    const int lane = threadIdx.x & 63;
    const int b = (int)blockIdx.x * 4 + (int)(threadIdx.x >> 6);
    if (b >= B) return;

    // segment bounds
    int s = wave_lb(idx, N, b, lane);
    int e = wave_lb(idx, N, b + 1, lane);

    // row stats; anchor row stays in registers for the whole segment
    const float4 a  = reinterpret_cast<const float4*>(A)[(size_t)b * 64 + lane];
    const float4 pv = reinterpret_cast<const float4*>(P)[(size_t)b * 64 + lane];
    float sa = DOT4(a, a);
    float sp = DOT4(pv, pv);
    float dq = DOT4(a, pv);
    sa = wave_reduce_sum(sa);
    sp = wave_reduce_sum(sp);
    dq = wave_reduce_sum(dq);
    float ia = 0.0f, ps = 0.0f;
    if (lane == 0) {
        ia = 1.0f / fmaxf(sqrtf(sa), 1e-12f);
        float ip = 1.0f / fmaxf(sqrtf(sp), 1e-12f);
        ps = dq * ia * ip * TEMP_INV;
    }
    ia = __shfl(ia, 0);
    ps = __shfl(ps, 0);

    // stream the segment, 4 rows per iteration
    const vf4* N4 = reinterpret_cast<const vf4*>(Ng);
    float mxa = -INFINITY, sea = 0.0f;   // live on lanes 0,16,32,48
    for (int j = s; j < e; j += 4) {
        vf4 n0 = {0.f, 0.f, 0.f, 0.f}, n1 = n0, n2 = n0, n3 = n0;
        n0 = N4[(size_t)j * 64 + lane];                    // j < e guaranteed
        if (j + 1 < e) n1 = N4[(size_t)(j + 1) * 64 + lane];
        if (j + 2 < e) n2 = N4[(size_t)(j + 2) * 64 + lane];
        if (j + 3 < e) n3 = N4[(size_t)(j + 3) * 64 + lane];

        float sn0 = DOT4(n0, n0), dp0 = DOT4(a, n0);
        float sn1 = DOT4(n1, n1), dp1 = DOT4(a, n1);
        float sn2 = DOT4(n2, n2), dp2 = DOT4(a, n2);
        float sn3 = DOT4(n3, n3), dp3 = DOT4(a, n3);

        // 8-value fold: 17 shuffles. sn_r -> lane 16r, dp_r -> lane 16r+8.
        float nv0 = merge2(sn0, sn2, 32, lane);
        float nv1 = merge2(dp0, dp2, 32, lane);
        float nv2 = merge2(sn1, sn3, 32, lane);
        float nv3 = merge2(dp1, dp3, 32, lane);
        float m0  = merge2(nv0, nv2, 16, lane);
        float m1  = merge2(nv1, nv3, 16, lane);
        float f   = merge2(m0,  m1,   8, lane);
        f += __shfl_xor(f, 4);
        f += __shfl_xor(f, 2);
        f += __shfl_xor(f, 1);

        float fdp = __shfl_down(f, 8);   // lane 16r: dp_r (f there = sn_r)
        if ((lane & 15) == 0) {
            int r = lane >> 4;
            if (j + r < e) {
                float t = fdp * (1.0f / fmaxf(sqrtf(f), 1e-12f)) * ia * TEMP_INV;
                mxa = fmaxf(mxa, t);
                sea += expf(t - TEMP_INV);
            }
        }
    }

    float mx = wave_reduce_max(mxa);
    float se = wave_reduce_sum(sea);
    if (lane == 0) {
        float l = 0.0f, c = 0.0f;
        if (e > s) {
            l = -ps + TEMP_INV + logf(se + expf(ps - TEMP_INV));
            c = (ps > mx) ? 1.0f : 0.0f;
        }
        loss_i[b] = l;
        corr[b]   = c;
    }
}

// Single-block deterministic reduce -> out[0]=loss, out[1]=accuracy
__global__ __launch_bounds__(1024)
void k_final(const float* __restrict__ loss_i, const float* __restrict__ corr,
             float* __restrict__ out, int B) {
    __shared__ float sl[16];
    __shared__ float sc[16];
    int tid = (int)threadIdx.x, lane = tid & 63, wid = tid >> 6;  // 16 waves
    float l = 0.0f, c = 0.0f;
    for (int i = tid; i < B; i += 1024) { l += loss_i[i]; c += corr[i]; }
    l = wave_reduce_sum(l);
    c = wave_reduce_sum(c);
    if (lane == 0) { sl[wid] = l; sc[wid] = c; }
    __syncthreads();
    if (wid == 0) {
        float lv = (lane < 16) ? sl[lane] : 0.0f;
        float cv = (lane < 16) ? sc[lane] : 0.0f;
        lv = wave_reduce_sum(lv);
        cv = wave_reduce_sum(cv);
        if (lane == 0) {
            out[0] = lv / (float)B;
            out[1] = cv / (float)B;
        }
    }
}

extern "C" void kernel_launch(void* const* d_in, const int* in_sizes, int n_in,
                              void* d_out, int out_size, void* d_ws, size_t ws_size,
                              hipStream_t stream) {
    const float* anchor    = (const float*)d_in[0];
    const float* positive  = (const float*)d_in[1];
    const float* negatives = (const float*)d_in[2];
    const int*   idx       = (const int*)d_in[3];

    const int D = 256;
    const int B = in_sizes[0] / D;   // 4096
    const int N = in_sizes[2] / D;   // 131072

    float* ws     = (float*)d_ws;
    float* loss_i = ws;        // B
    float* corr   = ws + B;    // B

    float* out = (float*)d_out;

    // one wave per batch row: 4096 waves = 1024 blocks (4 blocks/CU)
    k_fused<<<(B + 3) / 4, 256, 0, stream>>>(anchor, positive, negatives, idx,
                                             loss_i, corr, B, N);

    k_final<<<1, 1024, 0, stream>>>(loss_i, corr, out, B);
}

// Round 15
// 34.287 us; speedup vs baseline: 1.0146x; 1.0146x over previous
//
#include <hip/hip_runtime.h>
#include <math.h>

#define TEMP_INV (1.0f / 0.07f)   // also the fixed LSE shift M (sims bounded by 1/T)

typedef float vf4 __attribute__((ext_vector_type(4)));

#define DOT4(a, n) ((a).x*(n).x + (a).y*(n).y + (a).z*(n).z + (a).w*(n).w)

__device__ __forceinline__ float wave_reduce_sum(float v) {
    #pragma unroll
    for (int off = 32; off; off >>= 1) v += __shfl_down(v, off);
    return v;
}

__device__ __forceinline__ float wave_reduce_max(float v) {
    #pragma unroll
    for (int off = 32; off; off >>= 1) v = fmaxf(v, __shfl_down(v, off));
    return v;
}

// fold two value-streams into one register: lanes with (lane&span) carry hi.
__device__ __forceinline__ float merge2(float lo, float hi, int span, int lane) {
    float a = lo + __shfl_xor(lo, span);
    float b = hi + __shfl_xor(hi, span);
    return (lane & span) ? b : a;
}

// Persistent kernel (best measured variant, R12 = 34.05us):
// (1) one anchor/positive row per wave, (2) seg_start fill,
// (3) grid-strided negative chunks (4 rows / 4KB per iter).
// k_main runs at ~5.2 TB/s = ~82% of achievable read BW — at the practical
// ceiling for this access pattern (six structural levers all neutral).
__global__ __launch_bounds__(256, 8)
void k_main(const float* __restrict__ A, const float* __restrict__ P,
            const float* __restrict__ Ng, const int* __restrict__ idx,
            float* __restrict__ inv_na, float* __restrict__ pos_sim,
            float* __restrict__ raw, int* __restrict__ seg_start,
            int B, int N) {
    const int bid  = (int)blockIdx.x;
    const int wib  = threadIdx.x >> 6;
    const int lane = threadIdx.x & 63;
    const int wave = bid * 4 + wib;
    const int nwaves = (int)gridDim.x * 4;

    // ---- Phase 1: row stats (one row per wave; B <= nwaves) ----
    if (wave < B) {
        int b = wave;
        const float4 a = reinterpret_cast<const float4*>(A + (size_t)b * 256)[lane];
        const float4 p = reinterpret_cast<const float4*>(P + (size_t)b * 256)[lane];
        float sa = DOT4(a, a);
        float sp = DOT4(p, p);
        float dq = DOT4(a, p);
        sa = wave_reduce_sum(sa);
        sp = wave_reduce_sum(sp);
        dq = wave_reduce_sum(dq);
        if (lane == 0) {
            float ia = 1.0f / fmaxf(sqrtf(sa), 1e-12f);
            float ip = 1.0f / fmaxf(sqrtf(sp), 1e-12f);
            inv_na[b]  = ia;
            pos_sim[b] = dq * ia * ip * TEMP_INV;
        }
    }

    // ---- Phase 2: seg_start[v] = lower_bound(idx, v), v in [0,B] ----
    {
        int t = bid * 256 + (int)threadIdx.x;
        int stride = (int)gridDim.x * 256;
        for (int j = t; j <= N; j += stride) {
            if (j == 0) {
                int c = idx[0];
                for (int v = 0; v <= c; ++v) seg_start[v] = 0;
            } else if (j < N) {
                int prev = idx[j - 1], cur = idx[j];
                for (int v = prev + 1; v <= cur; ++v) seg_start[v] = j;
            } else {
                int prev = idx[N - 1];
                for (int v = prev + 1; v <= B; ++v) seg_start[v] = N;
            }
        }
    }

    // ---- Phase 3: negative sims, 4 rows per iteration ----
    const int nchunks = N >> 2;
    const float4* A4 = reinterpret_cast<const float4*>(A);
    const vf4* N4 = reinterpret_cast<const vf4*>(Ng);
    for (int chunk = wave; chunk < nchunks; chunk += nwaves) {
        int j0 = chunk << 2;
        int4 bi = *reinterpret_cast<const int4*>(idx + j0);
        int b0 = __builtin_amdgcn_readfirstlane(bi.x);
        int b1 = __builtin_amdgcn_readfirstlane(bi.y);
        int b2 = __builtin_amdgcn_readfirstlane(bi.z);
        int b3 = __builtin_amdgcn_readfirstlane(bi.w);

        const vf4 n0 = N4[(size_t)(j0 + 0) * 64 + lane];
        const vf4 n1 = N4[(size_t)(j0 + 1) * 64 + lane];
        const vf4 n2 = N4[(size_t)(j0 + 2) * 64 + lane];
        const vf4 n3 = N4[(size_t)(j0 + 3) * 64 + lane];

        const float4 a0 = A4[(size_t)b0 * 64 + lane];
        const float4 a1 = A4[(size_t)b1 * 64 + lane];
        const float4 a2 = A4[(size_t)b2 * 64 + lane];
        const float4 a3 = A4[(size_t)b3 * 64 + lane];

        float sn0 = DOT4(n0, n0);
        float dp0 = DOT4(a0, n0);
        float sn1 = DOT4(n1, n1);
        float dp1 = DOT4(a1, n1);
        float sn2 = DOT4(n2, n2);
        float dp2 = DOT4(a2, n2);
        float sn3 = DOT4(n3, n3);
        float dp3 = DOT4(a3, n3);

        // 8-value fold: 17 shuffles. sn_r -> lane 16r, dp_r -> lane 16r+8.
        float nv0 = merge2(sn0, sn2, 32, lane);
        float nv1 = merge2(dp0, dp2, 32, lane);
        float nv2 = merge2(sn1, sn3, 32, lane);
        float nv3 = merge2(dp1, dp3, 32, lane);
        float m0  = merge2(nv0, nv2, 16, lane);
        float m1  = merge2(nv1, nv3, 16, lane);
        float f   = merge2(m0,  m1,   8, lane);
        f += __shfl_xor(f, 4);
        f += __shfl_xor(f, 2);
        f += __shfl_xor(f, 1);

        float fdp = __shfl_down(f, 8);   // lane 16r receives dp_r
        if ((lane & 15) == 0) {
            int r = lane >> 4;
            raw[j0 + r] = fdp * (1.0f / fmaxf(sqrtf(f), 1e-12f)) * TEMP_INV;
        }
    }
}

// One wave per batch row (4 rows per 256-thread block): fixed-M single-pass LSE.
__global__ void k_seg(const float* __restrict__ raw, const int* __restrict__ seg_start,
                      const float* __restrict__ inv_na, const float* __restrict__ pos_sim,
                      float* __restrict__ loss_i, float* __restrict__ corr, int B) {
    int b = (int)blockIdx.x * 4 + (threadIdx.x >> 6);
    int lane = threadIdx.x & 63;
    if (b >= B) return;

    int s = seg_start[b];
    int e = seg_start[b + 1];

    float ps = pos_sim[b];
    float ia = inv_na[b];

    float l_val = 0.0f, c_val = 0.0f;
    if (e > s) {
        const float M = TEMP_INV;
        float mx = -INFINITY, se = 0.0f;
        for (int j = s + lane; j < e; j += 64) {
            float t = raw[j] * ia;
            mx = fmaxf(mx, t);
            se += expf(t - M);
        }
        mx = wave_reduce_max(mx);
        se = wave_reduce_sum(se);
        mx = __shfl(mx, 0);
        se = __shfl(se, 0);
        l_val = -ps + M + logf(se + expf(ps - M));
        c_val = (ps > mx) ? 1.0f : 0.0f;
    }
    if (lane == 0) { loss_i[b] = l_val; corr[b] = c_val; }
}

// Single-block deterministic reduce -> out[0]=loss, out[1]=accuracy
__global__ __launch_bounds__(1024)
void k_final(const float* __restrict__ loss_i, const float* __restrict__ corr,
             float* __restrict__ out, int B) {
    __shared__ float sl[16];
    __shared__ float sc[16];
    int tid = (int)threadIdx.x, lane = tid & 63, wid = tid >> 6;  // 16 waves
    float l = 0.0f, c = 0.0f;
    for (int i = tid; i < B; i += 1024) { l += loss_i[i]; c += corr[i]; }
    l = wave_reduce_sum(l);
    c = wave_reduce_sum(c);
    if (lane == 0) { sl[wid] = l; sc[wid] = c; }
    __syncthreads();
    if (wid == 0) {
        float lv = (lane < 16) ? sl[lane] : 0.0f;
        float cv = (lane < 16) ? sc[lane] : 0.0f;
        lv = wave_reduce_sum(lv);
        cv = wave_reduce_sum(cv);
        if (lane == 0) {
            out[0] = lv / (float)B;
            out[1] = cv / (float)B;
        }
    }
}

extern "C" void kernel_launch(void* const* d_in, const int* in_sizes, int n_in,
                              void* d_out, int out_size, void* d_ws, size_t ws_size,
                              hipStream_t stream) {
    const float* anchor    = (const float*)d_in[0];
    const float* positive  = (const float*)d_in[1];
    const float* negatives = (const float*)d_in[2];
    const int*   idx       = (const int*)d_in[3];

    const int D = 256;
    const int B = in_sizes[0] / D;   // 4096
    const int N = in_sizes[2] / D;   // 131072

    float* ws        = (float*)d_ws;
    float* raw       = ws;                      // N
    float* inv_na    = ws + N;                  // B
    float* pos_sim   = ws + N + B;              // B
    float* loss_i    = ws + N + 2 * B;          // B
    float* corr      = ws + N + 3 * B;          // B
    int*   seg_start = (int*)(ws + N + 4 * B);  // B + 1

    float* out = (float*)d_out;

    k_main<<<2048, 256, 0, stream>>>(anchor, positive, negatives, idx,
                                     inv_na, pos_sim, raw, seg_start, B, N);

    k_seg<<<(B + 3) / 4, 256, 0, stream>>>(raw, seg_start, inv_na, pos_sim,
                                           loss_i, corr, B);

    k_final<<<1, 1024, 0, stream>>>(loss_i, corr, out, B);
}